// Round 13
// baseline (93.914 us; speedup 1.0000x reference)
//
#include <hip/hip_runtime.h>

#define P_TERMS 24

typedef _Float16 f16x8 __attribute__((ext_vector_type(8)));
typedef float f32x16 __attribute__((ext_vector_type(16)));

static __device__ __forceinline__ unsigned pk2(float a, float b) {
  unsigned d;
  asm("v_cvt_pkrtz_f16_f32 %0, %1, %2" : "=v"(d) : "v"(a), "v"(b));
  return d;
}
// d.lo = a.lo + b.hi ; d.hi = a.hi + b.lo   (f16x2, swapped src1)
static __device__ __forceinline__ unsigned pkadd_sw(unsigned a, unsigned b) {
  unsigned d;
  asm("v_pk_add_f16 %0, %1, %2 op_sel:[0,1] op_sel_hi:[1,0]"
      : "=v"(d) : "v"(a), "v"(b));
  return d;
}

// -------- K0 (fused prep): chain cp[p]=A^pB per block; H8 rows + Ct8 ------
__global__ __launch_bounds__(256) void s4_prep(
    const float* __restrict__ A, const float* __restrict__ B,
    const float* __restrict__ C, const float* __restrict__ log_dt,
    _Float16* __restrict__ H8, _Float16* __restrict__ Ct8) {
  const int tid = threadIdx.x;
  const int bid = blockIdx.x;
  if (bid == 64) {  // Ct8[n/8][m][8] = C[m][n]
    const int m = tid;
#pragma unroll 1
    for (int n = 0; n < 64; ++n)
      Ct8[((size_t)(n >> 3) * 256 + m) * 8 + (n & 7)] = (_Float16)C[m * 64 + n];
    return;
  }
  __shared__ float cp[P_TERMS + 1][64];
  __shared__ float cur[64];
  if (tid < 64) { cur[tid] = B[tid]; cp[0][tid] = B[tid]; }
  __syncthreads();
  const int n = tid >> 2, g = tid & 3;
  for (int p = 1; p <= P_TERMS; ++p) {
    float s = 0.f;
    const int j0 = g * 16;
#pragma unroll
    for (int j = 0; j < 16; ++j) s += A[n * 64 + j0 + j] * cur[j0 + j];
    s += __shfl_xor(s, 1);
    s += __shfl_xor(s, 2);
    __syncthreads();
    if (g == 0) { cur[n] = s; cp[p][n] = s; }
    __syncthreads();
  }
  // H[bid, k] = sum_p binom(k,p) dt^p cp[p][bid]; layout [k/8][n][8]
  const float dt = __expf(log_dt[0]);
#pragma unroll 1
  for (int kk = tid; kk < 512; kk += 256) {
    float coef = 1.f, s = cp[0][bid];
#pragma unroll 1
    for (int p = 1; p <= P_TERMS; ++p) {
      coef *= dt * (float)(kk - p + 1) / (float)p;  // zero for p>kk
      s += coef * cp[p][bid];
    }
    H8[((size_t)(kk >> 3) * 64 + bid) * 8 + (kk & 7)] = (_Float16)s;
  }
}

// ---------------- K3: rank-64 factored  Y = dt*(G@H^T)@C^T + 2 u D --------
// Stage 1: Z^T[n,t] = mfma(A=H, B=G). Stage-1 D (t in lanes, n in regs)
// converted to stage-2 A-fragments IN REGISTERS via pk2 + permlane32_swap
// (semantics: new d.hi = old s.lo, new s.lo = old d.hi -> swap(W0,W2)
// yields W0=[X.lo|Y.lo], W2=[X.hi|Y.hi]). No Zl, no post-build barrier:
// waves decorrelate; 26.6 KB LDS -> 4 blocks/CU, 16 waves/CU.
__global__ __launch_bounds__(256, 4) void s4_main(
    const float* __restrict__ x, const _Float16* __restrict__ H8,
    const _Float16* __restrict__ Ct8, const float* __restrict__ Dvec,
    const float* __restrict__ log_dt, float* __restrict__ out) {
  __shared__ float us[512];    // u for this channel
  __shared__ uint4 UF8[1536];  // UF8[i] = f16{uf(i..i+7)}, uf(g)=u[g-512] guarded

  const int tid = threadIdx.x;
  const int bid = blockIdx.x;
  const int th = bid & 1;  // t half
  const int ch = bid >> 1;
  const int b = ch >> 8;
  const int d = ch & 255;

  for (int i = tid; i < 512; i += 256) us[i] = x[(b * 512 + i) * 256 + d];
  __syncthreads();
  {
    const int i0 = tid * 6;  // 256*6 = 1536 windows
    float w[14];
#pragma unroll
    for (int j = 0; j < 14; ++j) {
      const int g = i0 + j - 512;
      const float v = us[g & 511];
      w[j] = (g >= 0 && g < 512) ? v : 0.f;
    }
    unsigned P[13];
#pragma unroll
    for (int j = 0; j < 13; ++j) P[j] = pk2(w[j], w[j + 1]);
#pragma unroll
    for (int e = 0; e < 6; ++e)
      UF8[i0 + e] = make_uint4(P[e], P[e + 2], P[e + 4], P[e + 6]);
  }
  __syncthreads();

  const int lane = tid & 63;
  const int wid = tid >> 6;
  const int r = lane & 31;
  const int hi = lane >> 5;
  const int tw = wid * 64;        // local strip base (0..192)
  const int tg0 = th * 256 + tw;  // global strip base

  // ---------------- stage 1: Z^T = H @ G ----------------
  f32x16 acc[2][2];  // [ti][ni]
#pragma unroll
  for (int ti = 0; ti < 2; ++ti)
#pragma unroll
    for (int ni = 0; ni < 2; ++ni)
#pragma unroll
      for (int e = 0; e < 16; ++e) acc[ti][ni][e] = 0.f;

  int ifj = 512 + tg0 + r + hi * 8;  // F(j) tile0; tile1 at +32
  int irj = 505 + tg0 + r - hi * 8;  // R(j) tile0; tile1 at +32
  const _Float16* hp = H8 + hi * 512 + r * 8;

#pragma unroll 1
  for (int j = 0; j < 32; ++j) {
    const uint4 F0 = UF8[ifj];
    const uint4 R0 = UF8[irj];
    const uint4 F1 = UF8[ifj + 32];
    const uint4 R1 = UF8[irj + 32];
    const f16x8 h0 = *reinterpret_cast<const f16x8*>(hp);
    const f16x8 h1 = *reinterpret_cast<const f16x8*>(hp + 256);
    union { unsigned w[4]; f16x8 v; } g0, g1;
    g0.w[0] = pkadd_sw(F0.x, R0.w);
    g0.w[1] = pkadd_sw(F0.y, R0.z);
    g0.w[2] = pkadd_sw(F0.z, R0.y);
    g0.w[3] = pkadd_sw(F0.w, R0.x);
    g1.w[0] = pkadd_sw(F1.x, R1.w);
    g1.w[1] = pkadd_sw(F1.y, R1.z);
    g1.w[2] = pkadd_sw(F1.z, R1.y);
    g1.w[3] = pkadd_sw(F1.w, R1.x);
    __builtin_amdgcn_s_setprio(1);
    acc[0][0] = __builtin_amdgcn_mfma_f32_32x32x16_f16(h0, g0.v, acc[0][0], 0, 0, 0);
    acc[0][1] = __builtin_amdgcn_mfma_f32_32x32x16_f16(h1, g0.v, acc[0][1], 0, 0, 0);
    acc[1][0] = __builtin_amdgcn_mfma_f32_32x32x16_f16(h0, g1.v, acc[1][0], 0, 0, 0);
    acc[1][1] = __builtin_amdgcn_mfma_f32_32x32x16_f16(h1, g1.v, acc[1][1], 0, 0, 0);
    __builtin_amdgcn_s_setprio(0);
    ifj += 16;
    irj -= 16;
    hp += 1024;
  }

  // ---- Z -> stage-2 A-frags, in registers (pk2 + permlane32_swap) ----
  // Stage-1 D: row n = (reg&3)+8*(reg>>2)+4*hi+32*ni, col t = lane&31.
  // Frag[ks] words needed: w0=[X0.lo|X2.lo] w1=[X1.lo|X3.lo]
  //                        w2=[X0.hi|X2.hi] w3=[X1.hi|X3.hi]
  // where X0,X1 = packs of quad qe, X2,X3 = packs of quad qo.
  f16x8 zfrag[2][4];  // [ti][ks]
#pragma unroll
  for (int ti = 0; ti < 2; ++ti) {
#pragma unroll
    for (int ks = 0; ks < 4; ++ks) {
      const int ni = ks >> 1;
      const int qe = (2 * ks) & 3;
      const int qo = qe + 1;
      unsigned W0 = pk2(acc[ti][ni][4 * qe + 0], acc[ti][ni][4 * qe + 1]);
      unsigned W2 = pk2(acc[ti][ni][4 * qo + 0], acc[ti][ni][4 * qo + 1]);
      unsigned W1 = pk2(acc[ti][ni][4 * qe + 2], acc[ti][ni][4 * qe + 3]);
      unsigned W3 = pk2(acc[ti][ni][4 * qo + 2], acc[ti][ni][4 * qo + 3]);
      // swap(d,s): new d.hi = old s.lo ; new s.lo = old d.hi
      asm("v_permlane32_swap_b32 %0, %1" : "+v"(W0), "+v"(W2));
      asm("v_permlane32_swap_b32 %0, %1" : "+v"(W1), "+v"(W3));
      union { unsigned w[4]; f16x8 v; } zf;
      zf.w[0] = W0;
      zf.w[1] = W1;
      zf.w[2] = W2;
      zf.w[3] = W3;
      zfrag[ti][ks] = zf.v;
    }
  }

  // ---------------- stage 2: Y = Z @ C^T + 2uD ----------------
  const float dtv = __expf(log_dt[0]);
#pragma unroll 1
  for (int mp = 0; mp < 4; ++mp) {
    const int mb2 = mp * 64;
    f32x16 y[2][2];  // [ti][mi]
#pragma unroll
    for (int ti = 0; ti < 2; ++ti)
#pragma unroll
      for (int mi = 0; mi < 2; ++mi)
#pragma unroll
        for (int e = 0; e < 16; ++e) y[ti][mi][e] = 0.f;

#pragma unroll
    for (int ks = 0; ks < 4; ++ks) {
      const _Float16* cb = Ct8 + ((size_t)(2 * ks + hi) * 256 + mb2 + r) * 8;
      const f16x8 c0f = *reinterpret_cast<const f16x8*>(cb);
      const f16x8 c1f = *reinterpret_cast<const f16x8*>(cb + 256);
      __builtin_amdgcn_s_setprio(1);
      y[0][0] = __builtin_amdgcn_mfma_f32_32x32x16_f16(zfrag[0][ks], c0f, y[0][0], 0, 0, 0);
      y[0][1] = __builtin_amdgcn_mfma_f32_32x32x16_f16(zfrag[0][ks], c1f, y[0][1], 0, 0, 0);
      y[1][0] = __builtin_amdgcn_mfma_f32_32x32x16_f16(zfrag[1][ks], c0f, y[1][0], 0, 0, 0);
      y[1][1] = __builtin_amdgcn_mfma_f32_32x32x16_f16(zfrag[1][ks], c1f, y[1][1], 0, 0, 0);
      __builtin_amdgcn_s_setprio(0);
    }

#pragma unroll
    for (int ti = 0; ti < 2; ++ti) {
      const int tb2 = th * 256 + tw + ti * 32 + 4 * hi;
#pragma unroll
      for (int mi = 0; mi < 2; ++mi) {
        const int m = mb2 + mi * 32 + r;
        const float Dm = Dvec[m];
#pragma unroll
        for (int reg = 0; reg < 16; ++reg) {
          const int trow = tb2 + (reg & 3) + 8 * (reg >> 2);
          const float uv = us[trow];
          out[(((size_t)b * 512 + trow) * 256 + d) * 256 + m] =
              dtv * y[ti][mi][reg] + 2.f * uv * Dm;
        }
      }
    }
  }
}

extern "C" void kernel_launch(void* const* d_in, const int* in_sizes, int n_in,
                              void* d_out, int out_size, void* d_ws, size_t ws_size,
                              hipStream_t stream) {
  (void)in_sizes; (void)n_in; (void)out_size; (void)ws_size;
  const float* x = (const float*)d_in[0];
  const float* A = (const float*)d_in[1];
  const float* B = (const float*)d_in[2];
  const float* C = (const float*)d_in[3];
  const float* D = (const float*)d_in[4];
  const float* log_dt = (const float*)d_in[5];
  float* out = (float*)d_out;

  _Float16* H8 = (_Float16*)d_ws;                    // 512*64*2  = 64 KB
  _Float16* Ct8 = (_Float16*)((char*)d_ws + 65536);  // 64*256*2  = 32 KB

  s4_prep<<<65, 256, 0, stream>>>(A, B, C, log_dt, H8, Ct8);
  s4_main<<<1024, 256, 0, stream>>>(x, H8, Ct8, D, log_dt, out);
}

// Round 14
// 91.727 us; speedup vs baseline: 1.0238x; 1.0238x over previous
//
#include <hip/hip_runtime.h>

#define P_TERMS 24

typedef _Float16 f16x8 __attribute__((ext_vector_type(8)));
typedef float f32x16 __attribute__((ext_vector_type(16)));

static __device__ __forceinline__ unsigned pk2(float a, float b) {
  unsigned d;
  asm("v_cvt_pkrtz_f16_f32 %0, %1, %2" : "=v"(d) : "v"(a), "v"(b));
  return d;
}
// d.lo = a.lo + b.hi ; d.hi = a.hi + b.lo   (f16x2, swapped src1)
static __device__ __forceinline__ unsigned pkadd_sw(unsigned a, unsigned b) {
  unsigned d;
  asm("v_pk_add_f16 %0, %1, %2 op_sel:[0,1] op_sel_hi:[1,0]"
      : "=v"(d) : "v"(a), "v"(b));
  return d;
}

// -------- K0 (fused prep): chain cp[p]=A^pB per block; H8 rows + Ct8 ------
__global__ __launch_bounds__(256) void s4_prep(
    const float* __restrict__ A, const float* __restrict__ B,
    const float* __restrict__ C, const float* __restrict__ log_dt,
    _Float16* __restrict__ H8, _Float16* __restrict__ Ct8) {
  const int tid = threadIdx.x;
  const int bid = blockIdx.x;
  if (bid == 64) {  // Ct8[n/8][m][8] = C[m][n]
    const int m = tid;
#pragma unroll 1
    for (int n = 0; n < 64; ++n)
      Ct8[((size_t)(n >> 3) * 256 + m) * 8 + (n & 7)] = (_Float16)C[m * 64 + n];
    return;
  }
  __shared__ float cp[P_TERMS + 1][64];
  __shared__ float cur[64];
  if (tid < 64) { cur[tid] = B[tid]; cp[0][tid] = B[tid]; }
  __syncthreads();
  const int n = tid >> 2, g = tid & 3;
  for (int p = 1; p <= P_TERMS; ++p) {
    float s = 0.f;
    const int j0 = g * 16;
#pragma unroll
    for (int j = 0; j < 16; ++j) s += A[n * 64 + j0 + j] * cur[j0 + j];
    s += __shfl_xor(s, 1);
    s += __shfl_xor(s, 2);
    __syncthreads();
    if (g == 0) { cur[n] = s; cp[p][n] = s; }
    __syncthreads();
  }
  // H[bid, k] = sum_p binom(k,p) dt^p cp[p][bid]; layout [k/8][n][8]
  const float dt = __expf(log_dt[0]);
#pragma unroll 1
  for (int kk = tid; kk < 512; kk += 256) {
    float coef = 1.f, s = cp[0][bid];
#pragma unroll 1
    for (int p = 1; p <= P_TERMS; ++p) {
      coef *= dt * (float)(kk - p + 1) / (float)p;  // zero for p>kk
      s += coef * cp[p][bid];
    }
    H8[((size_t)(kk >> 3) * 64 + bid) * 8 + (kk & 7)] = (_Float16)s;
  }
}

// ---------------- Stage 1 (compute-only): Z^T = H @ G -> Z embedded in out
// Z(ch) f16[o=2ks+hi][t][8] (64 KB) lives at out rows t'=0..63 of channel ch:
// f16x8 at (o,t) <-> float4 at out[((b*512 + w0/256)*256 + d)*256 + w0%256],
// w0 = o*2048 + t*4.  Coalesced 16B/lane stores.
__global__ __launch_bounds__(256, 4) void s4_stage1(
    const float* __restrict__ x, const _Float16* __restrict__ H8,
    float* __restrict__ out) {
  __shared__ float us[512];    // u for this channel
  __shared__ uint4 UF8[1536];  // UF8[i] = f16{uf(i..i+7)}, uf(g)=u[g-512] guarded

  const int tid = threadIdx.x;
  const int bid = blockIdx.x;
  const int th = bid & 1;  // t half
  const int ch = bid >> 1;
  const int b = ch >> 8;
  const int d = ch & 255;

  for (int i = tid; i < 512; i += 256) us[i] = x[(b * 512 + i) * 256 + d];
  __syncthreads();
  {
    const int i0 = tid * 6;  // 256*6 = 1536 windows
    float w[14];
#pragma unroll
    for (int j = 0; j < 14; ++j) {
      const int g = i0 + j - 512;
      const float v = us[g & 511];
      w[j] = (g >= 0 && g < 512) ? v : 0.f;
    }
    unsigned P[13];
#pragma unroll
    for (int j = 0; j < 13; ++j) P[j] = pk2(w[j], w[j + 1]);
#pragma unroll
    for (int e = 0; e < 6; ++e)
      UF8[i0 + e] = make_uint4(P[e], P[e + 2], P[e + 4], P[e + 6]);
  }
  __syncthreads();

  const int lane = tid & 63;
  const int wid = tid >> 6;
  const int r = lane & 31;
  const int hi = lane >> 5;
  const int tw = wid * 64;        // local strip base (0..192)
  const int tg0 = th * 256 + tw;  // global strip base

  f32x16 acc[2][2];  // [ti][ni]
#pragma unroll
  for (int ti = 0; ti < 2; ++ti)
#pragma unroll
    for (int ni = 0; ni < 2; ++ni)
#pragma unroll
      for (int e = 0; e < 16; ++e) acc[ti][ni][e] = 0.f;

  int ifj = 512 + tg0 + r + hi * 8;  // F(j) tile0; tile1 at +32
  int irj = 505 + tg0 + r - hi * 8;  // R(j) tile0; tile1 at +32
  const _Float16* hp = H8 + hi * 512 + r * 8;

#pragma unroll 1
  for (int j = 0; j < 32; ++j) {
    const uint4 F0 = UF8[ifj];
    const uint4 R0 = UF8[irj];
    const uint4 F1 = UF8[ifj + 32];
    const uint4 R1 = UF8[irj + 32];
    const f16x8 h0 = *reinterpret_cast<const f16x8*>(hp);
    const f16x8 h1 = *reinterpret_cast<const f16x8*>(hp + 256);
    union { unsigned w[4]; f16x8 v; } g0, g1;
    g0.w[0] = pkadd_sw(F0.x, R0.w);
    g0.w[1] = pkadd_sw(F0.y, R0.z);
    g0.w[2] = pkadd_sw(F0.z, R0.y);
    g0.w[3] = pkadd_sw(F0.w, R0.x);
    g1.w[0] = pkadd_sw(F1.x, R1.w);
    g1.w[1] = pkadd_sw(F1.y, R1.z);
    g1.w[2] = pkadd_sw(F1.z, R1.y);
    g1.w[3] = pkadd_sw(F1.w, R1.x);
    __builtin_amdgcn_s_setprio(1);
    acc[0][0] = __builtin_amdgcn_mfma_f32_32x32x16_f16(h0, g0.v, acc[0][0], 0, 0, 0);
    acc[0][1] = __builtin_amdgcn_mfma_f32_32x32x16_f16(h1, g0.v, acc[0][1], 0, 0, 0);
    acc[1][0] = __builtin_amdgcn_mfma_f32_32x32x16_f16(h0, g1.v, acc[1][0], 0, 0, 0);
    acc[1][1] = __builtin_amdgcn_mfma_f32_32x32x16_f16(h1, g1.v, acc[1][1], 0, 0, 0);
    __builtin_amdgcn_s_setprio(0);
    ifj += 16;
    irj -= 16;
    hp += 1024;
  }

  // in-register transpose to A-frag layout (verified R13)
  f16x8 zfrag[2][4];  // [ti][ks]
#pragma unroll
  for (int ti = 0; ti < 2; ++ti) {
#pragma unroll
    for (int ks = 0; ks < 4; ++ks) {
      const int ni = ks >> 1;
      const int qe = (2 * ks) & 3;
      const int qo = qe + 1;
      unsigned W0 = pk2(acc[ti][ni][4 * qe + 0], acc[ti][ni][4 * qe + 1]);
      unsigned W2 = pk2(acc[ti][ni][4 * qo + 0], acc[ti][ni][4 * qo + 1]);
      unsigned W1 = pk2(acc[ti][ni][4 * qe + 2], acc[ti][ni][4 * qe + 3]);
      unsigned W3 = pk2(acc[ti][ni][4 * qo + 2], acc[ti][ni][4 * qo + 3]);
      asm("v_permlane32_swap_b32 %0, %1" : "+v"(W0), "+v"(W2));
      asm("v_permlane32_swap_b32 %0, %1" : "+v"(W1), "+v"(W3));
      union { unsigned w[4]; f16x8 v; } zf;
      zf.w[0] = W0;
      zf.w[1] = W1;
      zf.w[2] = W2;
      zf.w[3] = W3;
      zfrag[ti][ks] = zf.v;
    }
  }

  // store Z (coalesced 16B/lane)
#pragma unroll
  for (int ti = 0; ti < 2; ++ti) {
    const int tg = tg0 + ti * 32 + r;
#pragma unroll
    for (int ks = 0; ks < 4; ++ks) {
      const int w0 = (2 * ks + hi) * 2048 + tg * 4;
      float* p = out + (((size_t)b * 512 + (w0 >> 8)) * 256 + d) * 256 + (w0 & 255);
      *reinterpret_cast<f16x8*>(p) = zfrag[ti][ks];
    }
  }
}

// ---------------- Stage 2 (store-streaming): Y = dt*Z@C^T + 2uD ----------
// One block = one channel. Load all Z frags first, barrier (drains loads),
// then 2x4 panels of MFMA + coalesced stores overwrite the whole channel.
__global__ __launch_bounds__(256, 2) void s4_stage2(
    const float* __restrict__ x, const _Float16* __restrict__ Ct8,
    const float* __restrict__ Dvec, const float* __restrict__ log_dt,
    float* __restrict__ out) {
  __shared__ float us[512];
  const int tid = threadIdx.x;
  const int ch = blockIdx.x;
  const int b = ch >> 8;
  const int d = ch & 255;

  for (int i = tid; i < 512; i += 256) us[i] = x[(b * 512 + i) * 256 + d];

  const int lane = tid & 63;
  const int wid = tid >> 6;
  const int r = lane & 31;
  const int hi = lane >> 5;
  const int ts0 = wid * 128;  // wave strip: 128 t

  // load Z fragments (embedded in out by stage1)
  f16x8 zf[4][4];  // [ti][ks]
#pragma unroll
  for (int ti = 0; ti < 4; ++ti) {
    const int t = ts0 + ti * 32 + r;
#pragma unroll
    for (int ks = 0; ks < 4; ++ks) {
      const int w0 = (2 * ks + hi) * 2048 + t * 4;
      const float* p =
          out + (((size_t)b * 512 + (w0 >> 8)) * 256 + d) * 256 + (w0 & 255);
      zf[ti][ks] = *reinterpret_cast<const f16x8*>(p);
    }
  }
  __syncthreads();  // drains vmcnt: all Z reads complete before any store

  const float dtv = __expf(log_dt[0]);
#pragma unroll
  for (int tg = 0; tg < 2; ++tg) {  // compile-time (zf indexing, rule #20)
#pragma unroll 1
    for (int mp = 0; mp < 4; ++mp) {
      const int mb2 = mp * 64;
      f32x16 y[2][2];  // [ti2][mi]
#pragma unroll
      for (int ti2 = 0; ti2 < 2; ++ti2)
#pragma unroll
        for (int mi = 0; mi < 2; ++mi)
#pragma unroll
          for (int e = 0; e < 16; ++e) y[ti2][mi][e] = 0.f;

#pragma unroll
      for (int ks = 0; ks < 4; ++ks) {
        const _Float16* cb = Ct8 + ((size_t)(2 * ks + hi) * 256 + mb2 + r) * 8;
        const f16x8 c0f = *reinterpret_cast<const f16x8*>(cb);
        const f16x8 c1f = *reinterpret_cast<const f16x8*>(cb + 256);
        __builtin_amdgcn_s_setprio(1);
        y[0][0] = __builtin_amdgcn_mfma_f32_32x32x16_f16(zf[tg * 2 + 0][ks], c0f, y[0][0], 0, 0, 0);
        y[0][1] = __builtin_amdgcn_mfma_f32_32x32x16_f16(zf[tg * 2 + 0][ks], c1f, y[0][1], 0, 0, 0);
        y[1][0] = __builtin_amdgcn_mfma_f32_32x32x16_f16(zf[tg * 2 + 1][ks], c0f, y[1][0], 0, 0, 0);
        y[1][1] = __builtin_amdgcn_mfma_f32_32x32x16_f16(zf[tg * 2 + 1][ks], c1f, y[1][1], 0, 0, 0);
        __builtin_amdgcn_s_setprio(0);
      }

#pragma unroll
      for (int ti2 = 0; ti2 < 2; ++ti2) {
        const int tb2 = ts0 + (tg * 2 + ti2) * 32 + 4 * hi;
#pragma unroll
        for (int mi = 0; mi < 2; ++mi) {
          const int m = mb2 + mi * 32 + r;
          const float Dm = Dvec[m];
#pragma unroll
          for (int reg = 0; reg < 16; ++reg) {
            const int trow = tb2 + (reg & 3) + 8 * (reg >> 2);
            const float uv = us[trow];
            out[(((size_t)b * 512 + trow) * 256 + d) * 256 + m] =
                dtv * y[ti2][mi][reg] + 2.f * uv * Dm;
          }
        }
      }
    }
  }
}

extern "C" void kernel_launch(void* const* d_in, const int* in_sizes, int n_in,
                              void* d_out, int out_size, void* d_ws, size_t ws_size,
                              hipStream_t stream) {
  (void)in_sizes; (void)n_in; (void)out_size; (void)ws_size;
  const float* x = (const float*)d_in[0];
  const float* A = (const float*)d_in[1];
  const float* B = (const float*)d_in[2];
  const float* C = (const float*)d_in[3];
  const float* D = (const float*)d_in[4];
  const float* log_dt = (const float*)d_in[5];
  float* out = (float*)d_out;

  _Float16* H8 = (_Float16*)d_ws;                    // 512*64*2  = 64 KB
  _Float16* Ct8 = (_Float16*)((char*)d_ws + 65536);  // 64*256*2  = 32 KB

  s4_prep<<<65, 256, 0, stream>>>(A, B, C, log_dt, H8, Ct8);
  s4_stage1<<<1024, 256, 0, stream>>>(x, H8, out);
  s4_stage2<<<512, 256, 0, stream>>>(x, Ct8, D, log_dt, out);
}